// Round 15
// baseline (917.851 us; speedup 1.0000x reference)
//
#include <hip/hip_runtime.h>
#include <math.h>

#define BTOT 1024
#define LEN  2048
#define T    100
#define HID  128
#define BPW  2   // ROUND-15: batches per workgroup 4 -> 2 (grid 512, 2 blocks/CU)

// time-embedding dim constants (f64 argument scaling, f32 sincos)
#define C1 0.025118864315095794
#define C2 6.309573444801933e-04
#define C3 1.5848931924611134e-05
#define C4 3.9810717055349735e-07

#define TEMB(td) \
  float d0 = sinf((float)(td)); \
  float d1 = cosf((float)((td) * C1)); \
  float d2 = sinf((float)((td) * C2)); \
  float d3 = cosf((float)((td) * C3)); \
  float d4 = sinf((float)((td) * C4));

__device__ __forceinline__ float sig(float x) { return 1.0f / (1.0f + expf(-x)); }

using v2f = __attribute__((ext_vector_type(2))) float;
__device__ __forceinline__ v2f mkv2(float a, float b) { v2f r; r.x = a; r.y = b; return r; }

// DPP-based add: x + x_from_permuted_lane (VALU pipe).
template <int CTRL>
__device__ __forceinline__ float dppadd(float x) {
  int r = __builtin_amdgcn_update_dpp(0, __float_as_int(x), CTRL, 0xF, 0xF, false);
  return x + __int_as_float(r);
}
// full 64-lane sum; result valid in lane 0.
__device__ __forceinline__ float wred(float x) {
  x = dppadd<0xB1>(x);    // quad_perm xor1
  x = dppadd<0x4E>(x);    // quad_perm xor2
  x = dppadd<0x124>(x);   // row_ror:4
  x = dppadd<0x128>(x);   // row_ror:8
  x += __shfl_xor(x, 16);
  x += __shfl_xor(x, 32);
  return x;
}
// 4-lane quad sum (quad_perm only -- direction-unambiguous XOR semantics).
#define RED4(x) { x = dppadd<0xB1>(x); x = dppadd<0x4E>(x); }

// AGPR stash/read: "a" constraint allocates in the ACCUMULATOR half of the
// unified file, outside the 64-arch-VGPR budget (validated round 14: VGPR
// 64->128, WRITE 178MB->4KB, weights resident across all 100 iterations).
#define AGSTASH(a_, v_) asm volatile("v_accvgpr_write_b32 %0, %1" : "=a"(a_) : "v"(v_))
#define AGREAD(v_, a_)  asm volatile("v_accvgpr_read_b32 %0, %1" : "=v"(v_) : "a"(a_))

// ---------------- Phase A: attention (unchanged from rounds 12-14, passed) ----------------
__global__ __attribute__((amdgpu_flat_work_group_size(512, 512)))
void attn_k(const float* __restrict__ ta1,
            const float* __restrict__ ta2,
            float* __restrict__ att) {
  const int b = blockIdx.x, tid = threadIdx.x;
  const int wave = tid >> 6, lane = tid & 63;

  __shared__ float qlds[T][8];
  __shared__ float strip[8][T][8];

  if (tid < T) {
    double ct = (double)(tid + 1) * 0.1;
    TEMB(ct);
    qlds[tid][0] = d0 * 0.35355339059327373f;  // fold 1/sqrt(8)
    qlds[tid][1] = d1 * 0.35355339059327373f;
    qlds[tid][2] = d2 * 0.35355339059327373f;
    qlds[tid][3] = d3 * 0.35355339059327373f;
    qlds[tid][4] = d4 * 0.35355339059327373f;
  }

#define E5(i) float e##i##_0, e##i##_1, e##i##_2, e##i##_3, e##i##_4;
  E5(0) E5(1) E5(2) E5(3) E5(4) E5(5) E5(6) E5(7)
#undef E5
#define STAGE(i, expr) { double td_ = (double)(expr); \
    e##i##_0 = sinf((float)td_); \
    e##i##_1 = cosf((float)(td_ * C1)); \
    e##i##_2 = sinf((float)(td_ * C2)); \
    e##i##_3 = cosf((float)(td_ * C3)); \
    e##i##_4 = sinf((float)(td_ * C4)); }
  STAGE(0, ta1[b * LEN + tid +    0])
  STAGE(1, ta1[b * LEN + tid +  512])
  STAGE(2, ta1[b * LEN + tid + 1024])
  STAGE(3, ta1[b * LEN + tid + 1536])
  STAGE(4, ta2[b * LEN + tid +    0])
  STAGE(5, ta2[b * LEN + tid +  512])
  STAGE(6, ta2[b * LEN + tid + 1024])
  STAGE(7, ta2[b * LEN + tid + 1536])
#undef STAGE
#define PIN5(i) asm volatile("" : "+v"(e##i##_0), "+v"(e##i##_1), \
    "+v"(e##i##_2), "+v"(e##i##_3), "+v"(e##i##_4));
  PIN5(0) PIN5(1) PIN5(2) PIN5(3) PIN5(4) PIN5(5) PIN5(6) PIN5(7)
#undef PIN5

  __syncthreads();

  for (int t = 0; t < T; t++) {
    const float4 qv = *(const float4*)&qlds[t][0];
    const float q4 = qlds[t][4];
    float Wx = 0.f, Wy = 0.f, Wz = 0.f, Ww = 0.f, W4 = 0.f, sA = 0.f, sB = 0.f;
#define EV(i, S) { \
    float s = fmaf(qv.x, e##i##_0, fmaf(qv.y, e##i##_1, \
              fmaf(qv.z, e##i##_2, fmaf(qv.w, e##i##_3, q4 * e##i##_4)))); \
    float e = __expf(s); S += e; \
    Wx = fmaf(e, e##i##_0, Wx); Wy = fmaf(e, e##i##_1, Wy); \
    Wz = fmaf(e, e##i##_2, Wz); Ww = fmaf(e, e##i##_3, Ww); \
    W4 = fmaf(e, e##i##_4, W4); }
    EV(0, sA) EV(1, sA) EV(2, sA) EV(3, sA)
    EV(4, sB) EV(5, sB) EV(6, sB) EV(7, sB)
#undef EV

    float r0 = wred(Wx), r1 = wred(Wy), r2 = wred(Wz), r3 = wred(Ww);
    float r4 = wred(W4), r5 = wred(sA), r6 = wred(sB);
    if (lane == 0) {
      *(float4*)&strip[wave][t][0] = make_float4(r0, r1, r2, r3);
      strip[wave][t][4] = r4; strip[wave][t][5] = r5; strip[wave][t][6] = r6;
    }
  }
  __syncthreads();

  if (tid < T) {
    float f0 = 0.f, f1 = 0.f, f2 = 0.f, f3 = 0.f, f4 = 0.f, f5 = 0.f, f6 = 0.f;
#pragma unroll
    for (int w = 0; w < 8; w++) {
      float4 a = *(float4*)&strip[w][tid][0];
      float4 bq = *(float4*)&strip[w][tid][4];
      f0 += a.x; f1 += a.y; f2 += a.z; f3 += a.w;
      f4 += bq.x; f5 += bq.y; f6 += bq.z;
    }
    float inv = 1.0f / (f5 + f6);
    float* o8 = &att[(size_t)b * (T * 8) + (size_t)tid * 8];
    o8[0] = f0 * inv; o8[1] = f1 * inv; o8[2] = f2 * inv;
    o8[3] = f3 * inv; o8[4] = f4 * inv;
    o8[5] = 0.f; o8[6] = f5 * inv; o8[7] = f6 * inv;
  }
}

// ---------------- Phase B: LSTM -- AGPR weights, BPW=2, 2 blocks/CU ----------------
// ROUND-15 (from r14's profile: Occupancy 23% = 2 waves/SIMD, latency-bound;
// DS floor 3.8K cyc/t but measured 10.9K): grid 512 x 512 threads = 2
// blocks/CU = 4 waves/SIMD. Per-CU work invariant (320 DS insts/t), 2x waves
// to hide latency, per-thread FMA halves. Idle threads 256-271 prefetch the
// att-part of x(t+1) during the cell phase (disjoint LDS, no dependency).
#define XE(tb, b, e) (((tb) * BPW + (b)) * 160 + (e))

__global__ __attribute__((amdgpu_flat_work_group_size(512, 512)))
void lstm_k(const float* __restrict__ att,
            const float* __restrict__ u,
            const float* __restrict__ Wih,
            const float* __restrict__ Whh,
            const float* __restrict__ bih,
            const float* __restrict__ bhh,
            const float* __restrict__ w1g,
            const float* __restrict__ b1g,
            const float* __restrict__ w2g,
            const float* __restrict__ b2g,
            float* __restrict__ out) {
  const int tid = threadIdx.x;
  const int bg = blockIdx.x * BPW;
  const int q = tid >> 2, s = tid & 3;       // channel, 40-col segment
  const int lane = tid & 63;
  const int s10 = s * 10;

  __shared__ float4 xls4[2][BPW][40];        // dbuf [x(21)|pad|hx(128)|pad(8)] per batch
  __shared__ float4 glds[BPW][128];          // gate exchange: (batch, channel) -> {i,f,g,o}
  __shared__ float red2[BPW][2];             // head partials: 2 waves per batch
  __shared__ float tembT[101][5];            // temb(k*0.1) table
  __shared__ float uT[BPW][100];             // staged uniforms
  __shared__ int stL[2][BPW], stD[2][BPW], stH[2][BPW];
  float* xf = (float*)xls4;

  // ---- one-time: weights into AGPRs ----
#define DECL4(g, c) float agw##g##_##c##_0, agw##g##_##c##_1, agw##g##_##c##_2, agw##g##_##c##_3;
  DECL4(0,0) DECL4(0,1) DECL4(0,2) DECL4(0,3) DECL4(0,4) DECL4(0,5) DECL4(0,6) DECL4(0,7) DECL4(0,8) DECL4(0,9)
  DECL4(1,0) DECL4(1,1) DECL4(1,2) DECL4(1,3) DECL4(1,4) DECL4(1,5) DECL4(1,6) DECL4(1,7) DECL4(1,8) DECL4(1,9)
  DECL4(2,0) DECL4(2,1) DECL4(2,2) DECL4(2,3) DECL4(2,4) DECL4(2,5) DECL4(2,6) DECL4(2,7) DECL4(2,8) DECL4(2,9)
  DECL4(3,0) DECL4(3,1) DECL4(3,2) DECL4(3,3) DECL4(3,4) DECL4(3,5) DECL4(3,6) DECL4(3,7) DECL4(3,8) DECL4(3,9)
#undef DECL4
#define LD4(g, c) { \
    int E_ = 40 * s + 4 * (c); \
    float4 wv4_; \
    if (E_ >= 24 && E_ < 152) { \
      wv4_ = *(const float4*)(Whh + (size_t)(q + 128 * (g)) * HID + (E_ - 24)); \
    } else if (E_ < 24) { \
      wv4_.x = (E_ + 0 < 21) ? Wih[(q + 128 * (g)) * 21 + E_ + 0] : 0.f; \
      wv4_.y = (E_ + 1 < 21) ? Wih[(q + 128 * (g)) * 21 + E_ + 1] : 0.f; \
      wv4_.z = (E_ + 2 < 21) ? Wih[(q + 128 * (g)) * 21 + E_ + 2] : 0.f; \
      wv4_.w = (E_ + 3 < 21) ? Wih[(q + 128 * (g)) * 21 + E_ + 3] : 0.f; \
    } else { wv4_ = make_float4(0.f, 0.f, 0.f, 0.f); } \
    AGSTASH(agw##g##_##c##_0, wv4_.x); AGSTASH(agw##g##_##c##_1, wv4_.y); \
    AGSTASH(agw##g##_##c##_2, wv4_.z); AGSTASH(agw##g##_##c##_3, wv4_.w); }
  LD4(0,0) LD4(0,1) LD4(0,2) LD4(0,3) LD4(0,4) LD4(0,5) LD4(0,6) LD4(0,7) LD4(0,8) LD4(0,9)
  LD4(1,0) LD4(1,1) LD4(1,2) LD4(1,3) LD4(1,4) LD4(1,5) LD4(1,6) LD4(1,7) LD4(1,8) LD4(1,9)
  LD4(2,0) LD4(2,1) LD4(2,2) LD4(2,3) LD4(2,4) LD4(2,5) LD4(2,6) LD4(2,7) LD4(2,8) LD4(2,9)
  LD4(3,0) LD4(3,1) LD4(3,2) LD4(3,3) LD4(3,4) LD4(3,5) LD4(3,6) LD4(3,7) LD4(3,8) LD4(3,9)
#undef LD4

  // cell-role constants (cell threads are tid<256: b=tid>>7, ch=tid&127)
  const int chI = tid & 127;
  float bbc0 = bih[chI] + bhh[chI];
  float bbc1 = bih[chI + 128] + bhh[chI + 128];
  float bbc2 = bih[chI + 256] + bhh[chI + 256];
  float bbc3 = bih[chI + 384] + bhh[chI + 384];
  float wvc = 0.f;
#pragma unroll
  for (int j = 0; j < 5; j++) wvc = fmaf(w2g[j], w1g[j * HID + chI], wvc);
  float hconst = b2g[0];
#pragma unroll
  for (int j = 0; j < 5; j++) hconst = fmaf(w2g[j], b1g[j], hconst);
  asm volatile("" : "+v"(bbc0), "+v"(bbc1), "+v"(bbc2), "+v"(bbc3),
                    "+v"(wvc), "+v"(hconst));
  float cx = 0.f;

  // init: zero x buffers, temb table, stage u, event state
  for (int i = tid; i < 2 * BPW * 160; i += 512) xf[i] = 0.f;
  if (tid < 101) {
    double td = (double)tid * 0.1;
    TEMB(td);
    tembT[tid][0] = d0; tembT[tid][1] = d1; tembT[tid][2] = d2;
    tembT[tid][3] = d3; tembT[tid][4] = d4;
  }
  for (int i = tid; i < BPW * 100; i += 512) {
    int b = i / 100, tt = i - b * 100;
    uT[b][tt] = u[(size_t)(bg + b) * T + tt];
  }
  if (tid < BPW) { stL[0][tid] = 0; stD[0][tid] = 0; stH[0][tid] = 0; }
  __syncthreads();

  // x(t=0): att + ct_emb(0.1)=tembT[1]; m_emb stays 0 (no event yet)
  if (tid < BPW * 8) {
    int b = tid >> 3, j = tid & 7;
    xf[XE(0, b, j)] = att[(size_t)(bg + b) * (T * 8) + j];
  } else if (tid >= 64 && tid < 64 + BPW * 5) {
    int s2 = tid - 64, b = s2 / 5, j = s2 % 5;
    xf[XE(0, b, 16 + j)] = tembT[1][j];
  }
  __syncthreads();

#define GFMA(g, c) { \
    float t0_, t1_, t2_, t3_; \
    AGREAD(t0_, agw##g##_##c##_0); AGREAD(t1_, agw##g##_##c##_1); \
    AGREAD(t2_, agw##g##_##c##_2); AGREAD(t3_, agw##g##_##c##_3); \
    v2f wlo_ = mkv2(t0_, t1_), whi_ = mkv2(t2_, t3_); \
    a##g##0 = __builtin_elementwise_fma(wlo_, x0lo, a##g##0); \
    a##g##0 = __builtin_elementwise_fma(whi_, x0hi, a##g##0); \
    a##g##1 = __builtin_elementwise_fma(wlo_, x1lo, a##g##1); \
    a##g##1 = __builtin_elementwise_fma(whi_, x1hi, a##g##1); }

#define CH(c) { \
    float4 xb0_ = xls4[tb][0][s10 + (c)], xb1_ = xls4[tb][1][s10 + (c)]; \
    v2f x0lo = mkv2(xb0_.x, xb0_.y), x0hi = mkv2(xb0_.z, xb0_.w); \
    v2f x1lo = mkv2(xb1_.x, xb1_.y), x1hi = mkv2(xb1_.z, xb1_.w); \
    GFMA(0, c) GFMA(1, c) GFMA(2, c) GFMA(3, c) }

#define CALCEV(bb) \
    float z_ = hconst + red2[bb][0] + red2[bb][1]; \
    float hz_ = 1.f / (1.f + expf(-z_)); \
    int ev_ = (uT[bb][t] < hz_) ? 1 : 0; \
    int lastp_ = ev_ ? (t + 1) : stL[tb][bb]; \
    int hasp_ = stH[tb][bb] | ev_; \
    int dynp_ = ev_ ? 0 : (stD[tb][bb] + 1);

  for (int t = 0; t < T; t++) {
    const int tb = t & 1, tb1 = tb ^ 1;

    // ---- P1: pk-FMA over this thread's 40-col segment (weights from AGPR) ----
    v2f z2 = mkv2(0.f, 0.f);
    v2f a00 = z2, a01 = z2,
        a10 = z2, a11 = z2,
        a20 = z2, a21 = z2,
        a30 = z2, a31 = z2;
    CH(0) CH(1) CH(2) CH(3) CH(4) CH(5) CH(6) CH(7) CH(8) CH(9)

    float h00 = a00.x + a00.y, h01 = a01.x + a01.y;
    float h10 = a10.x + a10.y, h11 = a11.x + a11.y;
    float h20 = a20.x + a20.y, h21 = a21.x + a21.y;
    float h30 = a30.x + a30.y, h31 = a31.x + a31.y;
    RED4(h00) RED4(h01) RED4(h10) RED4(h11)
    RED4(h20) RED4(h21) RED4(h30) RED4(h31)
    if (s == 0) {   // quad lane 0 holds all 4 gates x BPW batches for channel q
      glds[0][q] = make_float4(h00, h10, h20, h30);
      glds[1][q] = make_float4(h01, h11, h21, h31);
    }
    __syncthreads();

    // ---- P2: dense cell (threads 0-255 = 2 batches x 128 channels);
    //      idle threads 256-271 prefetch att-part of x(t+1) (disjoint LDS) ----
    if (tid < 256) {
      int b = tid >> 7;
      float4 g4 = glds[b][chI];
      float gi = g4.x + bbc0, gf = g4.y + bbc1, gG = g4.z + bbc2, go = g4.w + bbc3;
      cx = sig(gf) * cx + sig(gi) * tanhf(gG);
      float hn = sig(go) * tanhf(cx);
      xf[XE(tb1, b, 24 + chI)] = hn;
      float pb = wred(wvc * hn);
      if (lane == 0) red2[b][(tid >> 6) & 1] = pb;
    } else if (tid < 256 + BPW * 8 && t < T - 1) {
      int s2 = tid - 256, b = s2 >> 3, j = s2 & 7;
      xf[XE(tb1, b, j)] = att[(size_t)(bg + b) * (T * 8) + (size_t)(t + 1) * 8 + j];
    }
    __syncthreads();

    // ---- P3: hazard/event finalize + small x(t+1) parts via temb table ----
    if (tid < BPW) {
      int b = tid;
      CALCEV(b);
      out[(size_t)t * BTOT + bg + b] = hz_;
      out[(size_t)T * BTOT + (size_t)t * BTOT + bg + b] = ev_ ? 1.f : 0.f;
      stL[tb1][b] = lastp_; stH[tb1][b] = hasp_; stD[tb1][b] = dynp_;
    }
    if (t < T - 1) {
      if (tid >= 32 && tid < 32 + BPW * 5) {
        int s2 = tid - 32, b = s2 / 5, j = s2 % 5;
        CALCEV(b);
        xf[XE(tb1, b, 8 + j)] = hasp_ ? tembT[lastp_][j] : 0.f;
      } else if (tid >= 52 && tid < 52 + BPW * 3) {
        int s2 = tid - 52, b = s2 / 3, j = s2 % 3;
        CALCEV(b);
        xf[XE(tb1, b, 13 + j)] = (j == 0 && hasp_) ? 1.f : 0.f;
      } else if (tid >= 64 && tid < 64 + BPW * 5) {
        int s2 = tid - 64, b = s2 / 5, j = s2 % 5;
        CALCEV(b);
        xf[XE(tb1, b, 16 + j)] = tembT[dynp_ + 1][j];
      }
    }
    __syncthreads();
  }
#undef CALCEV
#undef CH
#undef GFMA
}

extern "C" void kernel_launch(void* const* d_in, const int* in_sizes, int n_in,
                              void* d_out, int out_size, void* d_ws, size_t ws_size,
                              hipStream_t stream) {
  const float* ta1 = (const float*)d_in[0];
  const float* ta2 = (const float*)d_in[1];
  const float* u   = (const float*)d_in[2];
  const float* Wih = (const float*)d_in[3];
  const float* Whh = (const float*)d_in[4];
  const float* bih = (const float*)d_in[5];
  const float* bhh = (const float*)d_in[6];
  const float* w1  = (const float*)d_in[7];
  const float* b1  = (const float*)d_in[8];
  const float* w2  = (const float*)d_in[9];
  const float* b2  = (const float*)d_in[10];
  float* out = (float*)d_out;
  float* att = (float*)d_ws;   // 1024*100*8 floats = 3.28 MB scratch

  attn_k<<<dim3(BTOT), dim3(512), 0, stream>>>(ta1, ta2, att);
  lstm_k<<<dim3(BTOT / BPW), dim3(512), 0, stream>>>(att, u, Wih, Whh, bih, bhh,
                                                     w1, b1, w2, b2, out);
}